// Round 9
// baseline (475.611 us; speedup 1.0000x reference)
//
#include <hip/hip_runtime.h>
#include <cstdint>

#define NN   100000
#define EE   1600000
#define EMBD 256
#define DD   128
#define BBB  4096
#define LLL  50
#define NCLS 10

#define NB   196                  /* coarse buckets of 512 dst nodes */
#define BSH  9
#define EPB  4096                 /* edges per bin_k block */

#define FIXS 1048576.0f           /* 2^20 fixed-point scale for spmm accum */
#define INVS (1.0f / 1048576.0f)

// ---------------------------------------------------------------------------
// fp32 tiled GEMM: C[M, BN(grid.y)] = A[M,K] @ W[K,*] (+bias)
//  grid.z splits K into chunks of kper; chunk z writes C + z*M*ldc.
//  bidxg!=null: gather-A mode: A(r,k) =
//      k<3200 ? Z[bidx[r*50 + k/64]*64 + k%64] : S[r*64 + k%64]
//  Generalized loaders: ALOADS/WLOADS float4 loads per thread per BK-step.
// ---------------------------------------------------------------------------
template<int BM, int BN, int BK, int TM, int TN>
__global__ __launch_bounds__(256)
void gemm_f32(const float* __restrict__ Av, int lda,
              const float* __restrict__ W, int ldw,
              const float* __restrict__ bias,
              float* __restrict__ Cv, int ldc,
              int M, int ktot, int kper,
              const int* __restrict__ bidxg,
              const float* __restrict__ Sg)
{
  constexpr int TX = BN / TN;
  constexpr int TY = BM / TM;
  static_assert(TX * TY == 256, "thread mapping");
  static_assert(TN % 4 == 0, "epilogue uses 4-wide vectors");
  constexpr int AQ = BK / 4;
  constexpr int ALOADS = (BM * AQ) / 256;
  static_assert((BM * AQ) % 256 == 0, "A-tile load mapping");
  constexpr int WQ4 = BN / 4;
  constexpr int WLOADS = (BK * WQ4) / 256;
  static_assert((BK * WQ4) % 256 == 0, "W-tile load mapping");

  __shared__ float As[BK][BM + 4];
  __shared__ float Ws[BK][BN];

  const int tid = threadIdx.x;
  const int tx = tid % TX, ty = tid / TX;
  const int bm0 = blockIdx.x * BM;
  const int bn0 = blockIdx.y * BN;
  const int z = blockIdx.z;
  const int koff = z * kper;
  int kc = ktot - koff; if (kc > kper) kc = kper;
  W += bn0 + (size_t)koff * ldw;
  Cv += (size_t)z * (size_t)M * ldc;
  const float* biasp = bias ? bias + bn0 : nullptr;

  float acc[TM][TN];
#pragma unroll
  for (int i = 0; i < TM; ++i)
#pragma unroll
    for (int j = 0; j < TN; ++j) acc[i][j] = 0.f;

  for (int kt = 0; kt < kc; kt += BK) {
#pragma unroll
    for (int p = 0; p < ALOADS; ++p) {
      int f = tid + p * 256;
      int row = f / AQ, q = f % AQ;
      int arow = bm0 + row;
      float4 av = make_float4(0.f, 0.f, 0.f, 0.f);
      if (arow < M) {
        if (bidxg) {
          int k = koff + kt + (q << 2);
          int l = k >> 6, jj = k & 63;
          const float* ap = (l < LLL)
              ? (Av + (size_t)bidxg[arow * LLL + l] * 64 + jj)
              : (Sg + (size_t)arow * 64 + jj);
          av = *(const float4*)ap;
        } else {
          av = *(const float4*)(Av + (long long)arow * lda + koff + kt + (q << 2));
        }
      }
      As[(q << 2) + 0][row] = av.x;
      As[(q << 2) + 1][row] = av.y;
      As[(q << 2) + 2][row] = av.z;
      As[(q << 2) + 3][row] = av.w;
    }
#pragma unroll
    for (int p = 0; p < WLOADS; ++p) {
      int f = tid + p * 256;
      int krow = f / WQ4, c4 = f % WQ4;
      *(float4*)&Ws[krow][c4 << 2] =
          *(const float4*)(W + (long long)(kt + krow) * ldw + (c4 << 2));
    }
    __syncthreads();
#pragma unroll
    for (int kk = 0; kk < BK; ++kk) {
      float a[TM], b[TN];
      if constexpr (TM % 4 == 0) {
#pragma unroll
        for (int i = 0; i < TM; i += 4)
          *(float4*)&a[i] = *(const float4*)&As[kk][ty * TM + i];
      } else {
#pragma unroll
        for (int i = 0; i < TM; ++i) a[i] = As[kk][ty * TM + i];
      }
#pragma unroll
      for (int j = 0; j < TN; j += 4)
        *(float4*)&b[j] = *(const float4*)&Ws[kk][tx * TN + j];
#pragma unroll
      for (int i = 0; i < TM; ++i)
#pragma unroll
        for (int j = 0; j < TN; ++j)
          acc[i][j] = fmaf(a[i], b[j], acc[i][j]);
    }
    __syncthreads();
  }

#pragma unroll
  for (int i = 0; i < TM; ++i) {
    int r = bm0 + ty * TM + i;
    if (r >= M) continue;
#pragma unroll
    for (int j4 = 0; j4 < TN; j4 += 4) {
      float4 v = make_float4(acc[i][j4], acc[i][j4 + 1],
                             acc[i][j4 + 2], acc[i][j4 + 3]);
      if (biasp != nullptr) {
        v.x += biasp[tx * TN + j4 + 0]; v.y += biasp[tx * TN + j4 + 1];
        v.z += biasp[tx * TN + j4 + 2]; v.w += biasp[tx * TN + j4 + 3];
      }
      *(float4*)(Cv + (long long)r * ldc + bn0 + tx * TN + j4) = v;
    }
  }
}

// ---------------------------------------------------------------------------
// Weight fusion stage 1: T1 = wgc1@wgc2, T2 = lin1@wgc2, ta = bgc1@wgc2,
// tb = lin1b@wgc2  (all K=128 dots)
// ---------------------------------------------------------------------------
__global__ __launch_bounds__(256)
void fuse1_k(const float* __restrict__ wgc1, const float* __restrict__ lin1,
             const float* __restrict__ bgc1, const float* __restrict__ lin1b,
             const float* __restrict__ wgc2,
             float* __restrict__ T1, float* __restrict__ T2,
             float* __restrict__ ta, float* __restrict__ tb)
{
  int t = blockIdx.x * 256 + threadIdx.x;
  const float* Arow; float* outp; int n;
  if (t < 32768)      { n = t & 127; Arow = wgc1 + (t >> 7) * 128; outp = T1 + t; }
  else if (t < 65536) { int u = t - 32768; n = u & 127; Arow = lin1 + (u >> 7) * 128; outp = T2 + u; }
  else if (t < 65664) { n = t - 65536; Arow = bgc1;  outp = ta + n; }
  else if (t < 65792) { n = t - 65664; Arow = lin1b; outp = tb + n; }
  else return;
  float s = 0.f;
  for (int k = 0; k < 128; ++k) s = fmaf(Arow[k], wgc2[k * 128 + n], s);
  *outp = s;
}

// ---------------------------------------------------------------------------
// Weight fusion stage 2: Wab[:,0:64] = T1@w2, Wab[:,64:128] = T2@w2,
// bab = [ta@w2 | tb@w2], bc = bgc2@w2
// ---------------------------------------------------------------------------
__global__ __launch_bounds__(256)
void fuse2_k(const float* __restrict__ T1, const float* __restrict__ T2,
             const float* __restrict__ ta, const float* __restrict__ tb,
             const float* __restrict__ bgc2, const float* __restrict__ w2,
             float* __restrict__ Wab, float* __restrict__ bab,
             float* __restrict__ bcv)
{
  int t = blockIdx.x * 256 + threadIdx.x;
  const float* Arow; float* outp; int j;
  if (t < 32768) {
    int c = t & 127; j = c & 63;
    Arow = (c < 64 ? T1 : T2) + (t >> 7) * 128;
    outp = Wab + t;
  } else if (t < 32896) {
    int c = t - 32768; j = c & 63; Arow = (c < 64) ? ta : tb; outp = bab + c;
  } else if (t < 32960) {
    j = t - 32896; Arow = bgc2; outp = bcv + j;
  } else return;
  float s = 0.f;
  for (int k = 0; k < 128; ++k) s = fmaf(Arow[k], w2[k * 64 + j], s);
  *outp = s;
}

// ---------------------------------------------------------------------------
// CSR build: fine histogram -> 3-pass exclusive scan (-> rp), then
// two-level placement carrying (dst,src,w) sequentially so the spmms read a
// packed (src,w) array in CSR order with zero random metadata gathers.
// ---------------------------------------------------------------------------
__global__ __launch_bounds__(256)
void hist_k(const int* __restrict__ dst, int* __restrict__ cur)
{
  int e = blockIdx.x * 256 + threadIdx.x;
  if (e < EE) atomicAdd(&cur[dst[e]], 1);
}

__global__ __launch_bounds__(256)
void scan1_k(const int* __restrict__ cnt, int* __restrict__ rp1,
             int* __restrict__ part, int n)
{
  __shared__ int s[256];
  int t = threadIdx.x;
  int base = blockIdx.x * 1024 + t * 4;
  int a0 = (base + 0 < n) ? cnt[base + 0] : 0;
  int a1 = (base + 1 < n) ? cnt[base + 1] : 0;
  int a2 = (base + 2 < n) ? cnt[base + 2] : 0;
  int a3 = (base + 3 < n) ? cnt[base + 3] : 0;
  s[t] = a0 + a1 + a2 + a3;
  __syncthreads();
  for (int off = 1; off < 256; off <<= 1) {
    int v = (t >= off) ? s[t - off] : 0;
    __syncthreads();
    s[t] += v;
    __syncthreads();
  }
  int pre = t ? s[t - 1] : 0;
  int r0 = pre + a0, r1 = r0 + a1, r2 = r1 + a2, r3 = r2 + a3;
  if (base + 0 < n) rp1[base + 0] = r0;
  if (base + 1 < n) rp1[base + 1] = r1;
  if (base + 2 < n) rp1[base + 2] = r2;
  if (base + 3 < n) rp1[base + 3] = r3;
  if (t == 255) part[blockIdx.x] = s[255];
}

__global__ __launch_bounds__(256)
void scan2_k(int* __restrict__ part, int nb)
{
  __shared__ int s[256];
  int t = threadIdx.x;
  int v = (t < nb) ? part[t] : 0;
  s[t] = v;
  __syncthreads();
  for (int off = 1; off < 256; off <<= 1) {
    int u = (t >= off) ? s[t - off] : 0;
    __syncthreads();
    s[t] += u;
    __syncthreads();
  }
  if (t < nb) part[t] = s[t] - v;     // exclusive
}

__global__ __launch_bounds__(256)
void scan3_k(int* __restrict__ rp, const int* __restrict__ part, int n)
{
  int i = blockIdx.x * 256 + threadIdx.x;
  if (i == 0) rp[0] = 0;
  if (i < n) rp[1 + i] += part[i >> 10];
}

// gcur[c] = rp[c*512]  (coarse bucket write cursors)
__global__ __launch_bounds__(256)
void initcur_k(const int* __restrict__ rp, int* __restrict__ gcur)
{
  int t = threadIdx.x;
  if (t < NB) gcur[t] = rp[t << BSH];
}

// Level 1: bin edges into coarse buckets, streaming (dst,src,w) coalesced.
__global__ __launch_bounds__(256)
void bin_k(const int* __restrict__ edst, const int* __restrict__ esrc,
           const float* __restrict__ ew, int* __restrict__ gcur,
           int4* __restrict__ ebd)
{
  __shared__ int lcnt[NB];
  __shared__ int lbase[NB];
  const int tid = threadIdx.x;
  const int e0 = blockIdx.x * EPB;
  const int e1 = min(EE, e0 + EPB);
  for (int i = tid; i < NB; i += 256) lcnt[i] = 0;
  __syncthreads();
  int dv[16], sv[16], wv[16];
#pragma unroll
  for (int u = 0; u < 16; ++u) {
    int e = e0 + u * 256 + tid;
    if (e < e1) {
      dv[u] = edst[e];
      sv[u] = esrc[e];
      wv[u] = __float_as_int(ew[e]);
      atomicAdd(&lcnt[dv[u] >> BSH], 1);
    } else dv[u] = -1;
  }
  __syncthreads();
  for (int i = tid; i < NB; i += 256) {
    lbase[i] = atomicAdd(&gcur[i], lcnt[i]);
    lcnt[i] = 0;
  }
  __syncthreads();
#pragma unroll
  for (int u = 0; u < 16; ++u) {
    if (dv[u] >= 0) {
      int c = dv[u] >> BSH;
      int k = atomicAdd(&lcnt[c], 1);
      int4 p; p.x = dv[u]; p.y = sv[u]; p.z = wv[u]; p.w = 0;
      ebd[lbase[c] + k] = p;
    }
  }
}

// Level 2: one block per bucket; write packed (src,w) into CSR slots.
// sw writes stay inside a ~16KB L2-resident window -> no amplification.
__global__ __launch_bounds__(256)
void sort_k(const int4* __restrict__ ebd, const int* __restrict__ rp,
            int2* __restrict__ sw)
{
  __shared__ int rpl[512];
  __shared__ int lcur[512];
  const int c = blockIdx.x;
  const int n0 = c << BSH;
  const int n1 = min(NN, n0 + 512);
  const int nn = n1 - n0;
  const int tid = threadIdx.x;
  for (int i = tid; i < nn; i += 256) { rpl[i] = rp[n0 + i]; lcur[i] = 0; }
  __syncthreads();
  const int b0 = rp[n0];
  const int b1 = rp[n1];
  for (int i = b0 + tid; i < b1; i += 256) {
    int4 p = ebd[i];
    int li = p.x - n0;
    int k = atomicAdd(&lcur[li], 1);
    int2 q; q.x = p.y; q.y = p.z;
    sw[rpl[li] + k] = q;
  }
}

// ---------------------------------------------------------------------------
// CSR spmm on 64-wide f32 rows (src row stride GLD): one wave per dst node,
// lane owns one column. Packed sw=(src,wbits) read wave-uniform (broadcast);
// int fixed-point accumulate -> bit-deterministic.
//  MODE 1: out = acc*INVS + bias[lane]
//  MODE 2: out = n[d]*P[d,lane] + (1-n[d])*acc*INVS + bias[lane]
// ---------------------------------------------------------------------------
template<int MODE, int GLD>
__global__ __launch_bounds__(256)
void spmm64(const int* __restrict__ rp, const int2* __restrict__ sw,
            const float* __restrict__ Gf, float* __restrict__ xout,
            const float* __restrict__ bias, const float* __restrict__ npar,
            const float* __restrict__ QP)
{
  int widx = blockIdx.x * 4 + (threadIdx.x >> 6);
  if (widx >= NN) return;
  int lane = threadIdx.x & 63;
  int e0 = rp[widx], e1 = rp[widx + 1];
  int acc = 0;
  int j = e0;
  for (; j + 8 <= e1; j += 8) {
    float gv[8], wv[8];
#pragma unroll
    for (int u = 0; u < 8; ++u) {
      int2 q = sw[j + u];                       // wave-uniform -> broadcast
      wv[u] = __int_as_float(q.y);
      gv[u] = Gf[(size_t)q.x * GLD + lane];
    }
#pragma unroll
    for (int u = 0; u < 8; ++u)
      acc += __float2int_rn(gv[u] * wv[u] * FIXS);
  }
  for (; j < e1; ++j) {
    int2 q = sw[j];
    acc += __float2int_rn(Gf[(size_t)q.x * GLD + lane] *
                          __int_as_float(q.y) * FIXS);
  }
  float v = (float)acc * INVS;
  if (MODE == 1) {
    xout[(size_t)widx * 64 + lane] = v + bias[lane];
  } else {
    float nv = npar[widx];
    float p = QP[(size_t)widx * 128 + 64 + lane];
    xout[(size_t)widx * 64 + lane] = nv * p + (1.f - nv) * v + bias[lane];
  }
}

// ---------------------------------------------------------------------------
// S[b,:] = sum_l Z[bidx[b,l],:] - 49*b2   (Z rows already carry +b2 each)
// ---------------------------------------------------------------------------
__global__ __launch_bounds__(256)
void sumS_k(const float* __restrict__ Z, const int* __restrict__ bidx,
            const float* __restrict__ b2, float* __restrict__ S)
{
  int wv = threadIdx.x >> 6;
  int lane = threadIdx.x & 63;
  int b = blockIdx.x * 4 + wv;
  if (b >= BBB) return;
  const int* bi = bidx + (size_t)b * LLL;
  float s = 0.f;
  for (int l = 0; l < LLL; ++l)
    s += Z[(size_t)bi[l] * 64 + lane];
  S[(size_t)b * 64 + lane] = s - 49.f * b2[lane];
}

// ---------------------------------------------------------------------------
// sel = P4[0]+P4[1]+P4[2]+P4[3] + l1b  (fixed order -> deterministic)
// ---------------------------------------------------------------------------
__global__ __launch_bounds__(256)
void reduce4_k(const float* __restrict__ P4, const float* __restrict__ l1b,
               float* __restrict__ sel)
{
  int t = blockIdx.x * 256 + threadIdx.x;
  if (t >= BBB * 32) return;
  int r = t >> 5, c4 = t & 31;
  size_t off = (size_t)r * 128 + (c4 << 2);
  const size_t zs = (size_t)BBB * 128;
  float4 s0 = *(const float4*)(P4 + off);
  float4 s1 = *(const float4*)(P4 + zs + off);
  float4 s2 = *(const float4*)(P4 + 2 * zs + off);
  float4 s3 = *(const float4*)(P4 + 3 * zs + off);
  float4 b  = *(const float4*)(l1b + (c4 << 2));
  float4 o;
  o.x = ((s0.x + s1.x) + s2.x) + s3.x + b.x;
  o.y = ((s0.y + s1.y) + s2.y) + s3.y + b.y;
  o.z = ((s0.z + s1.z) + s2.z) + s3.z + b.z;
  o.w = ((s0.w + s1.w) + s2.w) + s3.w + b.w;
  *(float4*)(sel + off) = o;
}

// ---------------------------------------------------------------------------
// Classifier + argmax (first-max tie-break, matches jnp.argmax).
// ---------------------------------------------------------------------------
__global__ __launch_bounds__(256)
void cls_k(const float* __restrict__ sel, const float* __restrict__ Wc,
           const float* __restrict__ bc, float* __restrict__ outIdx)
{
  int wv = threadIdx.x >> 6;
  int lane = threadIdx.x & 63;
  int b = blockIdx.x * 4 + wv;
  if (b >= BBB) return;
  float logit = -1e30f;
  if (lane < NCLS) {
    float s = bc[lane];
    const float* sr = sel + (size_t)b * DD;
    for (int d = 0; d < DD; ++d) s = fmaf(sr[d], Wc[d * NCLS + lane], s);
    logit = s;
  }
  float best = -1e30f; int bi = 0;
  for (int c = 0; c < NCLS; ++c) {
    float v = __shfl(logit, c, 64);
    if (v > best) { best = v; bi = c; }
  }
  if (lane == 0) outIdx[b] = (float)bi;
}

// ---------------------------------------------------------------------------
extern "C" void kernel_launch(void* const* d_in, const int* in_sizes, int n_in,
                              void* d_out, int out_size, void* d_ws, size_t ws_size,
                              hipStream_t stream)
{
  const float* A1    = (const float*)d_in[0];
  const int*   esrc  = (const int*)d_in[1];
  const int*   edst  = (const int*)d_in[2];
  const float* ew    = (const float*)d_in[3];
  const int*   bidx  = (const int*)d_in[4];   // [B,1,L] == [B*L]
  const float* wgc1  = (const float*)d_in[5];
  const float* bgc1  = (const float*)d_in[6];
  const float* wgc2  = (const float*)d_in[7];
  const float* bgc2  = (const float*)d_in[8];
  const float* npar  = (const float*)d_in[9];
  const float* lin1  = (const float*)d_in[10];
  const float* lin1b = (const float*)d_in[11];
  const float* w2    = (const float*)d_in[12];
  const float* b2    = (const float*)d_in[13];
  const float* l1w   = (const float*)d_in[14];
  const float* l1b   = (const float*)d_in[15];
  const float* clsw  = (const float*)d_in[16];
  const float* clsb  = (const float*)d_in[17];

  float* out = (float*)d_out;
  float* sel = out + BBB;

  // workspace layout (peak ~91.9 MB; proven floor from round 1 is 104.67 MB)
  // ebd (25.6 MB) overlaps QP: dead before the QP GEMM launches (stream order).
  uint8_t* ws   = (uint8_t*)d_ws;
  float*   QP   = (float*)(ws);                 // 51.2 MB [N,128]; Z reuses 1st half
  int4*    ebd  = (int4*) (ws);                 // 25.6 MB [E] (d,s,w) - CSR build only
  float*   G    = (float*)(ws + 51200000);      // 25.6 MB [N,64]; P4 reuses it
  float*   Z    = (float*)(ws);                 // 25.6 MB [N,64] (over QP)
  float*   P4   = (float*)(ws + 51200000);      //  8.4 MB 4x[B,128] (over G)
  int2*    sw   = (int2*) (ws + 76800000);      // 12.8 MB packed (src,w) CSR order
  int*     rp   = (int*)  (ws + 89600000);      //  0.4 MB (N+1)
  int*     cur  = (int*)  (ws + 90000016);      //  0.4 MB (hist; reused as gcur)
  int*     part = (int*)  (ws + 90400016);      //  512 B
  float*   S    = (float*)(ws + 90400528);      //  1.0 MB [B,64]
  float*   T1   = (float*)(ws + 91449104);      // 128 KB [256,128]
  float*   T2   = (float*)(ws + 91580176);      // 128 KB
  float*   Wab  = (float*)(ws + 91711248);      // 128 KB [256,128]
  float*   ta   = (float*)(ws + 91842320);      // 512 B
  float*   tb   = (float*)(ws + 91842832);      // 512 B
  float*   bab  = (float*)(ws + 91843344);      // 512 B [128]
  float*   bcv  = (float*)(ws + 91843856);      // 256 B [64]

  dim3 blk(256);

  // ---- weight fusion (2 launches) ----
  hipLaunchKernelGGL(fuse1_k, dim3(257), blk, 0, stream,
      wgc1, lin1, bgc1, lin1b, wgc2, T1, T2, ta, tb);
  hipLaunchKernelGGL(fuse2_k, dim3(129), blk, 0, stream,
      T1, T2, ta, tb, bgc2, w2, Wab, bab, bcv);

  // ---- CSR build ----
  hipMemsetAsync(cur, 0, NN * 4, stream);
  hipLaunchKernelGGL(hist_k, dim3(EE / 256), blk, 0, stream, edst, cur);
  hipLaunchKernelGGL(scan1_k, dim3(98), blk, 0, stream, cur, rp + 1, part, NN);
  hipLaunchKernelGGL(scan2_k, dim3(1), blk, 0, stream, part, 98);
  hipLaunchKernelGGL(scan3_k, dim3(391), blk, 0, stream, rp, part, NN);
  hipLaunchKernelGGL(initcur_k, dim3(1), blk, 0, stream, rp, cur);
  hipLaunchKernelGGL(bin_k, dim3((EE + EPB - 1) / EPB), blk, 0, stream,
      edst, esrc, ew, cur, ebd);
  hipLaunchKernelGGL(sort_k, dim3(NB), blk, 0, stream, ebd, rp, sw);

  // ---- QP = A1 @ Wab + bab  [N,128]  (Q = cols 0..63, P = cols 64..127) ----
  hipLaunchKernelGGL((gemm_f32<128,128,16,8,8>), dim3(782, 1, 1), blk, 0, stream,
      A1, EMBD, Wab, 128, bab, QP, 128,
      NN, EMBD, EMBD, (const int*)nullptr, (const float*)nullptr);

  // ---- G = n*P + (1-n)*spmm(Q) + bc   (combine fused into spmm epilogue) ----
  hipLaunchKernelGGL((spmm64<2,128>), dim3(NN / 4), blk, 0, stream,
      rp, sw, QP, G, bcv, npar, QP);

  // ---- Z = spmm(G) + b2  [N,64] (overwrites QP's first half) ----
  hipLaunchKernelGGL((spmm64<1,64>), dim3(NN / 4), blk, 0, stream,
      rp, sw, G, Z, b2, (const float*)nullptr, (const float*)nullptr);

  // ---- S[b] = sum_l Z[bidx[b,l]] - 49*b2 ----
  hipLaunchKernelGGL(sumS_k, dim3(BBB / 4), blk, 0, stream, Z, bidx, b2, S);

  // ---- P4[z] = [gather(Z)|S] @ l1w (K-chunk z)  grid (128,2,4) ----
  hipLaunchKernelGGL((gemm_f32<32,64,32,2,4>), dim3(BBB / 32, 2, 4), blk, 0, stream,
      Z, 64, l1w, DD, (const float*)nullptr, P4, DD,
      BBB, (LLL + 1) * 64, 13 * 64, bidx, S);

  // ---- sel = sum_z P4[z] + l1b ----
  hipLaunchKernelGGL(reduce4_k, dim3(BBB * 32 / 256), blk, 0, stream, P4, l1b, sel);

  // ---- argmax(sel @ classifier + bias) -> out[0:B] ----
  hipLaunchKernelGGL(cls_k, dim3(BBB / 4), blk, 0, stream, sel, clsw, clsb, out);
}

// Round 10
// 418.497 us; speedup vs baseline: 1.1365x; 1.1365x over previous
//
#include <hip/hip_runtime.h>
#include <cstdint>

#define NN   100000
#define EE   1600000
#define EMBD 256
#define DD   128
#define BBB  4096
#define LLL  50
#define NCLS 10

#define NB   196                  /* coarse buckets of 512 dst nodes */
#define BSH  9
#define EPB  4096                 /* edges per cnt_k/bin_k block */

#define FIXS 1048576.0f           /* 2^20 fixed-point scale for spmm accum */
#define INVS (1.0f / 1048576.0f)

// ---------------------------------------------------------------------------
// fp32 tiled GEMM: C[M, BN(grid.y)] = A[M,K] @ W[K,*] (+bias)
//  grid.z splits K into chunks of kper; chunk z writes C + z*M*ldc.
//  bidxg!=null: gather-A mode: A(r,k) =
//      k<3200 ? Z[bidx[r*50 + k/64]*64 + k%64] : S[r*64 + k%64]
//  Cs!=null: split-store mode: col<64 -> Cv[r*64+col], col>=64 -> Cs[r*64+col-64]
// ---------------------------------------------------------------------------
template<int BM, int BN, int BK, int TM, int TN>
__global__ __launch_bounds__(256)
void gemm_f32(const float* __restrict__ Av, int lda,
              const float* __restrict__ W, int ldw,
              const float* __restrict__ bias,
              float* __restrict__ Cv, int ldc,
              int M, int ktot, int kper,
              const int* __restrict__ bidxg,
              const float* __restrict__ Sg,
              float* __restrict__ Cs)
{
  constexpr int TX = BN / TN;
  constexpr int TY = BM / TM;
  static_assert(TX * TY == 256, "thread mapping");
  static_assert(TN % 4 == 0, "epilogue uses 4-wide vectors");
  constexpr int AQ = BK / 4;
  constexpr int ALOADS = (BM * AQ) / 256;
  static_assert((BM * AQ) % 256 == 0, "A-tile load mapping");
  constexpr int WQ4 = BN / 4;
  constexpr int WLOADS = (BK * WQ4) / 256;
  static_assert((BK * WQ4) % 256 == 0, "W-tile load mapping");

  __shared__ float As[BK][BM + 4];
  __shared__ float Ws[BK][BN];

  const int tid = threadIdx.x;
  const int tx = tid % TX, ty = tid / TX;
  const int bm0 = blockIdx.x * BM;
  const int bn0 = blockIdx.y * BN;
  const int z = blockIdx.z;
  const int koff = z * kper;
  int kc = ktot - koff; if (kc > kper) kc = kper;
  W += bn0 + (size_t)koff * ldw;
  Cv += (Cs == nullptr) ? (size_t)z * (size_t)M * ldc : 0;
  const float* biasp = bias ? bias + bn0 : nullptr;

  float acc[TM][TN];
#pragma unroll
  for (int i = 0; i < TM; ++i)
#pragma unroll
    for (int j = 0; j < TN; ++j) acc[i][j] = 0.f;

  for (int kt = 0; kt < kc; kt += BK) {
#pragma unroll
    for (int p = 0; p < ALOADS; ++p) {
      int f = tid + p * 256;
      int row = f / AQ, q = f % AQ;
      int arow = bm0 + row;
      float4 av = make_float4(0.f, 0.f, 0.f, 0.f);
      if (arow < M) {
        if (bidxg) {
          int k = koff + kt + (q << 2);
          int l = k >> 6, jj = k & 63;
          const float* ap = (l < LLL)
              ? (Av + (size_t)bidxg[arow * LLL + l] * 64 + jj)
              : (Sg + (size_t)arow * 64 + jj);
          av = *(const float4*)ap;
        } else {
          av = *(const float4*)(Av + (long long)arow * lda + koff + kt + (q << 2));
        }
      }
      As[(q << 2) + 0][row] = av.x;
      As[(q << 2) + 1][row] = av.y;
      As[(q << 2) + 2][row] = av.z;
      As[(q << 2) + 3][row] = av.w;
    }
#pragma unroll
    for (int p = 0; p < WLOADS; ++p) {
      int f = tid + p * 256;
      int krow = f / WQ4, c4 = f % WQ4;
      *(float4*)&Ws[krow][c4 << 2] =
          *(const float4*)(W + (long long)(kt + krow) * ldw + (c4 << 2));
    }
    __syncthreads();
#pragma unroll
    for (int kk = 0; kk < BK; ++kk) {
      float a[TM], b[TN];
      if constexpr (TM % 4 == 0) {
#pragma unroll
        for (int i = 0; i < TM; i += 4)
          *(float4*)&a[i] = *(const float4*)&As[kk][ty * TM + i];
      } else {
#pragma unroll
        for (int i = 0; i < TM; ++i) a[i] = As[kk][ty * TM + i];
      }
#pragma unroll
      for (int j = 0; j < TN; j += 4)
        *(float4*)&b[j] = *(const float4*)&Ws[kk][tx * TN + j];
#pragma unroll
      for (int i = 0; i < TM; ++i)
#pragma unroll
        for (int j = 0; j < TN; ++j)
          acc[i][j] = fmaf(a[i], b[j], acc[i][j]);
    }
    __syncthreads();
  }

#pragma unroll
  for (int i = 0; i < TM; ++i) {
    int r = bm0 + ty * TM + i;
    if (r >= M) continue;
#pragma unroll
    for (int j4 = 0; j4 < TN; j4 += 4) {
      float4 v = make_float4(acc[i][j4], acc[i][j4 + 1],
                             acc[i][j4 + 2], acc[i][j4 + 3]);
      if (biasp != nullptr) {
        v.x += biasp[tx * TN + j4 + 0]; v.y += biasp[tx * TN + j4 + 1];
        v.z += biasp[tx * TN + j4 + 2]; v.w += biasp[tx * TN + j4 + 3];
      }
      int col = bn0 + tx * TN + j4;
      float* cp;
      if (Cs != nullptr)
        cp = (col < 64) ? (Cv + (long long)r * 64 + col)
                        : (Cs + (long long)r * 64 + (col - 64));
      else
        cp = Cv + (long long)r * ldc + col;
      *(float4*)cp = v;
    }
  }
}

// ---------------------------------------------------------------------------
// Weight fusion stage 1: T1 = wgc1@wgc2, T2 = lin1@wgc2, ta = bgc1@wgc2,
// tb = lin1b@wgc2  (all K=128 dots)
// ---------------------------------------------------------------------------
__global__ __launch_bounds__(256)
void fuse1_k(const float* __restrict__ wgc1, const float* __restrict__ lin1,
             const float* __restrict__ bgc1, const float* __restrict__ lin1b,
             const float* __restrict__ wgc2,
             float* __restrict__ T1, float* __restrict__ T2,
             float* __restrict__ ta, float* __restrict__ tb)
{
  int t = blockIdx.x * 256 + threadIdx.x;
  const float* Arow; float* outp; int n;
  if (t < 32768)      { n = t & 127; Arow = wgc1 + (t >> 7) * 128; outp = T1 + t; }
  else if (t < 65536) { int u = t - 32768; n = u & 127; Arow = lin1 + (u >> 7) * 128; outp = T2 + u; }
  else if (t < 65664) { n = t - 65536; Arow = bgc1;  outp = ta + n; }
  else if (t < 65792) { n = t - 65664; Arow = lin1b; outp = tb + n; }
  else return;
  float s = 0.f;
  for (int k = 0; k < 128; ++k) s = fmaf(Arow[k], wgc2[k * 128 + n], s);
  *outp = s;
}

// ---------------------------------------------------------------------------
// Weight fusion stage 2: Wab[:,0:64] = T1@w2, Wab[:,64:128] = T2@w2,
// bab = [ta@w2 | tb@w2], bc = bgc2@w2
// ---------------------------------------------------------------------------
__global__ __launch_bounds__(256)
void fuse2_k(const float* __restrict__ T1, const float* __restrict__ T2,
             const float* __restrict__ ta, const float* __restrict__ tb,
             const float* __restrict__ bgc2, const float* __restrict__ w2,
             float* __restrict__ Wab, float* __restrict__ bab,
             float* __restrict__ bcv)
{
  int t = blockIdx.x * 256 + threadIdx.x;
  const float* Arow; float* outp; int j;
  if (t < 32768) {
    int c = t & 127; j = c & 63;
    Arow = (c < 64 ? T1 : T2) + (t >> 7) * 128;
    outp = Wab + t;
  } else if (t < 32896) {
    int c = t - 32768; j = c & 63; Arow = (c < 64) ? ta : tb; outp = bab + c;
  } else if (t < 32960) {
    j = t - 32896; Arow = bgc2; outp = bcv + j;
  } else return;
  float s = 0.f;
  for (int k = 0; k < 128; ++k) s = fmaf(Arow[k], w2[k * 64 + j], s);
  *outp = s;
}

// ---------------------------------------------------------------------------
// CSR build v3: coarse count -> 1-block scan -> bin (bucket-grouped (d,s,w))
// -> sort (per-bucket LDS fine histogram + scan -> rp + packed sw).
// No 100K-wide random atomics anywhere.
// ---------------------------------------------------------------------------
__global__ __launch_bounds__(256)
void cnt_k(const int* __restrict__ edst, int* __restrict__ gbkt)
{
  __shared__ int l[NB];
  const int tid = threadIdx.x;
  for (int i = tid; i < NB; i += 256) l[i] = 0;
  __syncthreads();
  const int e0 = blockIdx.x * EPB;
  const int e1 = min(EE, e0 + EPB);
#pragma unroll
  for (int u = 0; u < 16; ++u) {
    int e = e0 + u * 256 + tid;
    if (e < e1) atomicAdd(&l[edst[e] >> BSH], 1);
  }
  __syncthreads();
  for (int i = tid; i < NB; i += 256)
    if (l[i]) atomicAdd(&gbkt[i], l[i]);
}

// exclusive scan of 196 bucket counts -> bbase[0..NB], gcur; rp[NN]=E
__global__ __launch_bounds__(256)
void scanB_k(const int* __restrict__ gbkt, int* __restrict__ bbase,
             int* __restrict__ gcur, int* __restrict__ rp)
{
  __shared__ int s[256];
  int t = threadIdx.x;
  int v = (t < NB) ? gbkt[t] : 0;
  s[t] = v;
  __syncthreads();
  for (int off = 1; off < 256; off <<= 1) {
    int u = (t >= off) ? s[t - off] : 0;
    __syncthreads();
    s[t] += u;
    __syncthreads();
  }
  if (t < NB) {
    int ex = s[t] - v;
    bbase[t] = ex;
    gcur[t] = ex;
  }
  if (t == 0) { bbase[NB] = EE; rp[NN] = EE; }
}

// Level 1: bin edges into coarse buckets, streaming (dst,src,w) coalesced.
__global__ __launch_bounds__(256)
void bin_k(const int* __restrict__ edst, const int* __restrict__ esrc,
           const float* __restrict__ ew, int* __restrict__ gcur,
           int4* __restrict__ ebd)
{
  __shared__ int lcnt[NB];
  __shared__ int lbase[NB];
  const int tid = threadIdx.x;
  const int e0 = blockIdx.x * EPB;
  const int e1 = min(EE, e0 + EPB);
  for (int i = tid; i < NB; i += 256) lcnt[i] = 0;
  __syncthreads();
  int dv[16], sv[16], wv[16];
#pragma unroll
  for (int u = 0; u < 16; ++u) {
    int e = e0 + u * 256 + tid;
    if (e < e1) {
      dv[u] = edst[e];
      sv[u] = esrc[e];
      wv[u] = __float_as_int(ew[e]);
      atomicAdd(&lcnt[dv[u] >> BSH], 1);
    } else dv[u] = -1;
  }
  __syncthreads();
  for (int i = tid; i < NB; i += 256) {
    lbase[i] = atomicAdd(&gcur[i], lcnt[i]);
    lcnt[i] = 0;
  }
  __syncthreads();
#pragma unroll
  for (int u = 0; u < 16; ++u) {
    if (dv[u] >= 0) {
      int c = dv[u] >> BSH;
      int k = atomicAdd(&lcnt[c], 1);
      int4 p; p.x = dv[u]; p.y = sv[u]; p.z = wv[u]; p.w = 0;
      ebd[lbase[c] + k] = p;
    }
  }
}

// Level 2: per bucket: LDS fine-histogram its ebd segment, LDS exclusive
// scan (512), write rp, then place packed (src,w) into CSR slots.
__global__ __launch_bounds__(256)
void sort_k(const int4* __restrict__ ebd, const int* __restrict__ bbase,
            int* __restrict__ rp, int2* __restrict__ sw)
{
  __shared__ int hist[512];
  __shared__ int excl[512];
  __shared__ int s2[256];
  __shared__ int lcur[512];
  const int c = blockIdx.x;
  const int n0 = c << BSH;
  const int n1 = min(NN, n0 + 512);
  const int nn = n1 - n0;
  const int tid = threadIdx.x;
  for (int i = tid; i < 512; i += 256) { hist[i] = 0; lcur[i] = 0; }
  __syncthreads();
  const int b0 = bbase[c];
  const int b1 = bbase[c + 1];
  for (int i = b0 + tid; i < b1; i += 256)
    atomicAdd(&hist[ebd[i].x - n0], 1);
  __syncthreads();
  int a0 = hist[2 * tid], a1 = hist[2 * tid + 1];
  s2[tid] = a0 + a1;
  __syncthreads();
  for (int off = 1; off < 256; off <<= 1) {
    int u = (tid >= off) ? s2[tid - off] : 0;
    __syncthreads();
    s2[tid] += u;
    __syncthreads();
  }
  int pe = tid ? s2[tid - 1] : 0;
  excl[2 * tid] = pe;
  excl[2 * tid + 1] = pe + a0;
  if (2 * tid < nn)     rp[n0 + 2 * tid]     = b0 + pe;
  if (2 * tid + 1 < nn) rp[n0 + 2 * tid + 1] = b0 + pe + a0;
  __syncthreads();
  for (int i = b0 + tid; i < b1; i += 256) {
    int4 p = ebd[i];
    int li = p.x - n0;
    int k = atomicAdd(&lcur[li], 1);
    int2 q; q.x = p.y; q.y = p.z;
    sw[b0 + excl[li] + k] = q;
  }
}

// ---------------------------------------------------------------------------
// CSR spmm on compact 64-wide f32 rows: one wave per dst node, lane owns one
// column. Packed sw=(src,wbits) read wave-uniform (broadcast); int
// fixed-point accumulate -> bit-deterministic.
//  MODE 1: out = acc*INVS + bias[lane]
//  MODE 2: out = n[d]*P[d,lane] + (1-n[d])*acc*INVS + bias[lane]
// ---------------------------------------------------------------------------
template<int MODE>
__global__ __launch_bounds__(256)
void spmm64(const int* __restrict__ rp, const int2* __restrict__ sw,
            const float* __restrict__ Gf, float* __restrict__ xout,
            const float* __restrict__ bias, const float* __restrict__ npar,
            const float* __restrict__ Pb)
{
  int widx = blockIdx.x * 4 + (threadIdx.x >> 6);
  if (widx >= NN) return;
  int lane = threadIdx.x & 63;
  int e0 = rp[widx], e1 = rp[widx + 1];
  int acc = 0;
  int j = e0;
  for (; j + 8 <= e1; j += 8) {
    float gv[8], wv[8];
#pragma unroll
    for (int u = 0; u < 8; ++u) {
      int2 q = sw[j + u];                       // wave-uniform -> broadcast
      wv[u] = __int_as_float(q.y);
      gv[u] = Gf[(size_t)q.x * 64 + lane];
    }
#pragma unroll
    for (int u = 0; u < 8; ++u)
      acc += __float2int_rn(gv[u] * wv[u] * FIXS);
  }
  for (; j < e1; ++j) {
    int2 q = sw[j];
    acc += __float2int_rn(Gf[(size_t)q.x * 64 + lane] *
                          __int_as_float(q.y) * FIXS);
  }
  float v = (float)acc * INVS;
  if (MODE == 1) {
    xout[(size_t)widx * 64 + lane] = v + bias[lane];
  } else {
    float nv = npar[widx];
    float p = Pb[(size_t)widx * 64 + lane];
    xout[(size_t)widx * 64 + lane] = nv * p + (1.f - nv) * v + bias[lane];
  }
}

// ---------------------------------------------------------------------------
// S[b,:] = sum_l Z[bidx[b,l],:] - 49*b2   (Z rows already carry +b2 each)
// ---------------------------------------------------------------------------
__global__ __launch_bounds__(256)
void sumS_k(const float* __restrict__ Z, const int* __restrict__ bidx,
            const float* __restrict__ b2, float* __restrict__ S)
{
  int wv = threadIdx.x >> 6;
  int lane = threadIdx.x & 63;
  int b = blockIdx.x * 4 + wv;
  if (b >= BBB) return;
  const int* bi = bidx + (size_t)b * LLL;
  float s = 0.f;
  for (int l = 0; l < LLL; ++l)
    s += Z[(size_t)bi[l] * 64 + lane];
  S[(size_t)b * 64 + lane] = s - 49.f * b2[lane];
}

// ---------------------------------------------------------------------------
// sel = P4[0]+P4[1]+P4[2]+P4[3] + l1b  (fixed order -> deterministic)
// ---------------------------------------------------------------------------
__global__ __launch_bounds__(256)
void reduce4_k(const float* __restrict__ P4, const float* __restrict__ l1b,
               float* __restrict__ sel)
{
  int t = blockIdx.x * 256 + threadIdx.x;
  if (t >= BBB * 32) return;
  int r = t >> 5, c4 = t & 31;
  size_t off = (size_t)r * 128 + (c4 << 2);
  const size_t zs = (size_t)BBB * 128;
  float4 s0 = *(const float4*)(P4 + off);
  float4 s1 = *(const float4*)(P4 + zs + off);
  float4 s2 = *(const float4*)(P4 + 2 * zs + off);
  float4 s3 = *(const float4*)(P4 + 3 * zs + off);
  float4 b  = *(const float4*)(l1b + (c4 << 2));
  float4 o;
  o.x = ((s0.x + s1.x) + s2.x) + s3.x + b.x;
  o.y = ((s0.y + s1.y) + s2.y) + s3.y + b.y;
  o.z = ((s0.z + s1.z) + s2.z) + s3.z + b.z;
  o.w = ((s0.w + s1.w) + s2.w) + s3.w + b.w;
  *(float4*)(sel + off) = o;
}

// ---------------------------------------------------------------------------
// Classifier + argmax (first-max tie-break, matches jnp.argmax).
// ---------------------------------------------------------------------------
__global__ __launch_bounds__(256)
void cls_k(const float* __restrict__ sel, const float* __restrict__ Wc,
           const float* __restrict__ bc, float* __restrict__ outIdx)
{
  int wv = threadIdx.x >> 6;
  int lane = threadIdx.x & 63;
  int b = blockIdx.x * 4 + wv;
  if (b >= BBB) return;
  float logit = -1e30f;
  if (lane < NCLS) {
    float s = bc[lane];
    const float* sr = sel + (size_t)b * DD;
    for (int d = 0; d < DD; ++d) s = fmaf(sr[d], Wc[d * NCLS + lane], s);
    logit = s;
  }
  float best = -1e30f; int bi = 0;
  for (int c = 0; c < NCLS; ++c) {
    float v = __shfl(logit, c, 64);
    if (v > best) { best = v; bi = c; }
  }
  if (lane == 0) outIdx[b] = (float)bi;
}

// ---------------------------------------------------------------------------
extern "C" void kernel_launch(void* const* d_in, const int* in_sizes, int n_in,
                              void* d_out, int out_size, void* d_ws, size_t ws_size,
                              hipStream_t stream)
{
  const float* A1    = (const float*)d_in[0];
  const int*   esrc  = (const int*)d_in[1];
  const int*   edst  = (const int*)d_in[2];
  const float* ew    = (const float*)d_in[3];
  const int*   bidx  = (const int*)d_in[4];   // [B,1,L] == [B*L]
  const float* wgc1  = (const float*)d_in[5];
  const float* bgc1  = (const float*)d_in[6];
  const float* wgc2  = (const float*)d_in[7];
  const float* bgc2  = (const float*)d_in[8];
  const float* npar  = (const float*)d_in[9];
  const float* lin1  = (const float*)d_in[10];
  const float* lin1b = (const float*)d_in[11];
  const float* w2    = (const float*)d_in[12];
  const float* b2    = (const float*)d_in[13];
  const float* l1w   = (const float*)d_in[14];
  const float* l1b   = (const float*)d_in[15];
  const float* clsw  = (const float*)d_in[16];
  const float* clsb  = (const float*)d_in[17];

  float* out = (float*)d_out;
  float* sel = out + BBB;

  // workspace layout (peak ~91.9 MB; proven floor from round 1 is 104.67 MB)
  //  ws+0      : ebd (25.6 MB, CSR build)  -> Qbuf [N,64] -> Z [N,64]
  //  ws+25.6M  : Pbuf [N,64] (dead after spmm1)
  //  ws+51.2M  : G [N,64] -> P4 (8.4 MB)
  uint8_t* ws   = (uint8_t*)d_ws;
  int4*    ebd  = (int4*) (ws);                 // 25.6 MB
  float*   Qb   = (float*)(ws);                 // 25.6 MB (after sort_k)
  float*   Z    = (float*)(ws);                 // 25.6 MB (after spmm1)
  float*   Pb   = (float*)(ws + 25600000);      // 25.6 MB
  float*   G    = (float*)(ws + 51200000);      // 25.6 MB
  float*   P4   = (float*)(ws + 51200000);      //  8.4 MB (after spmm2)
  int2*    sw   = (int2*) (ws + 76800000);      // 12.8 MB packed (src,w)
  int*     rp   = (int*)  (ws + 89600000);      //  0.4 MB (N+1)
  int*     gbkt = (int*)  (ws + 90000016);      //  784 B bucket counts
  int*     gcur = (int*)  (ws + 90001040);      //  784 B bucket cursors
  int*     bbase= (int*)  (ws + 90002064);      //  788 B bucket bases (NB+1)
  float*   S    = (float*)(ws + 90400528);      //  1.0 MB [B,64]
  float*   T1   = (float*)(ws + 91449104);      // 128 KB [256,128]
  float*   T2   = (float*)(ws + 91580176);      // 128 KB
  float*   Wab  = (float*)(ws + 91711248);      // 128 KB [256,128]
  float*   ta   = (float*)(ws + 91842320);      // 512 B
  float*   tb   = (float*)(ws + 91842832);      // 512 B
  float*   bab  = (float*)(ws + 91843344);      // 512 B [128]
  float*   bcv  = (float*)(ws + 91843856);      // 256 B [64]

  dim3 blk(256);
  const int gEB = (EE + EPB - 1) / EPB;         // 391

  // ---- weight fusion (2 launches) ----
  hipLaunchKernelGGL(fuse1_k, dim3(257), blk, 0, stream,
      wgc1, lin1, bgc1, lin1b, wgc2, T1, T2, ta, tb);
  hipLaunchKernelGGL(fuse2_k, dim3(129), blk, 0, stream,
      T1, T2, ta, tb, bgc2, w2, Wab, bab, bcv);

  // ---- CSR build (coarse count -> scan -> bin -> per-bucket sort) ----
  hipMemsetAsync(gbkt, 0, NB * 4, stream);
  hipLaunchKernelGGL(cnt_k, dim3(gEB), blk, 0, stream, edst, gbkt);
  hipLaunchKernelGGL(scanB_k, dim3(1), blk, 0, stream, gbkt, bbase, gcur, rp);
  hipLaunchKernelGGL(bin_k, dim3(gEB), blk, 0, stream, edst, esrc, ew, gcur, ebd);
  hipLaunchKernelGGL(sort_k, dim3(NB), blk, 0, stream, ebd, bbase, rp, sw);

  // ---- Q|P = A1 @ Wab + bab, split-stored compact [N,64] each ----
  hipLaunchKernelGGL((gemm_f32<64,128,32,8,4>), dim3(1563, 1, 1), blk, 0, stream,
      A1, EMBD, Wab, 128, bab, Qb, 64,
      NN, EMBD, EMBD, (const int*)nullptr, (const float*)nullptr, Pb);

  // ---- G = n*P + (1-n)*spmm(Q) + bc   (combine fused into spmm epilogue) ----
  hipLaunchKernelGGL((spmm64<2>), dim3(NN / 4), blk, 0, stream,
      rp, sw, Qb, G, bcv, npar, Pb);

  // ---- Z = spmm(G) + b2  [N,64] (overwrites Qbuf) ----
  hipLaunchKernelGGL((spmm64<1>), dim3(NN / 4), blk, 0, stream,
      rp, sw, G, Z, b2, (const float*)nullptr, (const float*)nullptr);

  // ---- S[b] = sum_l Z[bidx[b,l]] - 49*b2 ----
  hipLaunchKernelGGL(sumS_k, dim3(BBB / 4), blk, 0, stream, Z, bidx, b2, S);

  // ---- P4[z] = [gather(Z)|S] @ l1w (K-chunk z)  grid (128,2,4) ----
  hipLaunchKernelGGL((gemm_f32<32,64,32,2,4>), dim3(BBB / 32, 2, 4), blk, 0, stream,
      Z, 64, l1w, DD, (const float*)nullptr, P4, DD,
      BBB, (LLL + 1) * 64, 13 * 64, bidx, S, (float*)nullptr);

  // ---- sel = sum_z P4[z] + l1b ----
  hipLaunchKernelGGL(reduce4_k, dim3(BBB * 32 / 256), blk, 0, stream, P4, l1b, sel);

  // ---- argmax(sel @ classifier + bias) -> out[0:B] ----
  hipLaunchKernelGGL(cls_k, dim3(BBB / 4), blk, 0, stream, sel, clsw, clsb, out);
}

// Round 11
// 376.659 us; speedup vs baseline: 1.2627x; 1.1111x over previous
//
#include <hip/hip_runtime.h>
#include <cstdint>

#define NN   100000
#define EE   1600000
#define EMBD 256
#define DD   128
#define BBB  4096
#define LLL  50
#define NCLS 10

#define NB   196                  /* coarse buckets of 512 dst nodes */
#define BSH  9
#define EPB  4096                 /* edges per cnt_k/bin_k block */

#define FIXS 1048576.0f           /* 2^20 fixed-point scale for spmm accum */
#define INVS (1.0f / 1048576.0f)

typedef __attribute__((ext_vector_type(8))) short bf16x8;
typedef __attribute__((ext_vector_type(4))) float f32x4;

__device__ __forceinline__ ushort f2bf(float f) {
  uint32_t u = __float_as_uint(f);
  u += 0x7fffu + ((u >> 16) & 1u);        // round-to-nearest-even
  return (ushort)(u >> 16);
}
__device__ __forceinline__ float bf2f(ushort h) {
  return __uint_as_float(((uint32_t)h) << 16);
}

// ---------------------------------------------------------------------------
// fp32 tiled GEMM (kept for the gather-GEMM): C[M,BN(grid.y)] = A@W (+bias)
//  grid.z splits K into chunks of kper; chunk z writes C + z*M*ldc.
//  bidxg!=null: gather-A mode: A(r,k) =
//      k<3200 ? Z[bidx[r*50 + k/64]*64 + k%64] : S[r*64 + k%64]
// ---------------------------------------------------------------------------
template<int BM, int BN, int BK, int TM, int TN>
__global__ __launch_bounds__(256)
void gemm_f32(const float* __restrict__ Av, int lda,
              const float* __restrict__ W, int ldw,
              const float* __restrict__ bias,
              float* __restrict__ Cv, int ldc,
              int M, int ktot, int kper,
              const int* __restrict__ bidxg,
              const float* __restrict__ Sg)
{
  constexpr int TX = BN / TN;
  constexpr int TY = BM / TM;
  static_assert(TX * TY == 256, "thread mapping");
  static_assert(TN % 4 == 0, "epilogue uses 4-wide vectors");
  constexpr int AQ = BK / 4;
  constexpr int ALOADS = (BM * AQ) / 256;
  static_assert((BM * AQ) % 256 == 0, "A-tile load mapping");
  constexpr int WQ4 = BN / 4;
  constexpr int WLOADS = (BK * WQ4) / 256;
  static_assert((BK * WQ4) % 256 == 0, "W-tile load mapping");

  __shared__ float As[BK][BM + 4];
  __shared__ float Ws[BK][BN];

  const int tid = threadIdx.x;
  const int tx = tid % TX, ty = tid / TX;
  const int bm0 = blockIdx.x * BM;
  const int bn0 = blockIdx.y * BN;
  const int z = blockIdx.z;
  const int koff = z * kper;
  int kc = ktot - koff; if (kc > kper) kc = kper;
  W += bn0 + (size_t)koff * ldw;
  Cv += (size_t)z * (size_t)M * ldc;
  const float* biasp = bias ? bias + bn0 : nullptr;

  float acc[TM][TN];
#pragma unroll
  for (int i = 0; i < TM; ++i)
#pragma unroll
    for (int j = 0; j < TN; ++j) acc[i][j] = 0.f;

  for (int kt = 0; kt < kc; kt += BK) {
#pragma unroll
    for (int p = 0; p < ALOADS; ++p) {
      int f = tid + p * 256;
      int row = f / AQ, q = f % AQ;
      int arow = bm0 + row;
      float4 av = make_float4(0.f, 0.f, 0.f, 0.f);
      if (arow < M) {
        if (bidxg) {
          int k = koff + kt + (q << 2);
          int l = k >> 6, jj = k & 63;
          const float* ap = (l < LLL)
              ? (Av + (size_t)bidxg[arow * LLL + l] * 64 + jj)
              : (Sg + (size_t)arow * 64 + jj);
          av = *(const float4*)ap;
        } else {
          av = *(const float4*)(Av + (long long)arow * lda + koff + kt + (q << 2));
        }
      }
      As[(q << 2) + 0][row] = av.x;
      As[(q << 2) + 1][row] = av.y;
      As[(q << 2) + 2][row] = av.z;
      As[(q << 2) + 3][row] = av.w;
    }
#pragma unroll
    for (int p = 0; p < WLOADS; ++p) {
      int f = tid + p * 256;
      int krow = f / WQ4, c4 = f % WQ4;
      *(float4*)&Ws[krow][c4 << 2] =
          *(const float4*)(W + (long long)(kt + krow) * ldw + (c4 << 2));
    }
    __syncthreads();
#pragma unroll
    for (int kk = 0; kk < BK; ++kk) {
      float a[TM], b[TN];
      if constexpr (TM % 4 == 0) {
#pragma unroll
        for (int i = 0; i < TM; i += 4)
          *(float4*)&a[i] = *(const float4*)&As[kk][ty * TM + i];
      } else {
#pragma unroll
        for (int i = 0; i < TM; ++i) a[i] = As[kk][ty * TM + i];
      }
#pragma unroll
      for (int j = 0; j < TN; j += 4)
        *(float4*)&b[j] = *(const float4*)&Ws[kk][tx * TN + j];
#pragma unroll
      for (int i = 0; i < TM; ++i)
#pragma unroll
        for (int j = 0; j < TN; ++j)
          acc[i][j] = fmaf(a[i], b[j], acc[i][j]);
    }
    __syncthreads();
  }

#pragma unroll
  for (int i = 0; i < TM; ++i) {
    int r = bm0 + ty * TM + i;
    if (r >= M) continue;
#pragma unroll
    for (int j4 = 0; j4 < TN; j4 += 4) {
      float4 v = make_float4(acc[i][j4], acc[i][j4 + 1],
                             acc[i][j4 + 2], acc[i][j4 + 3]);
      if (biasp != nullptr) {
        v.x += biasp[tx * TN + j4 + 0]; v.y += biasp[tx * TN + j4 + 1];
        v.z += biasp[tx * TN + j4 + 2]; v.w += biasp[tx * TN + j4 + 3];
      }
      *(float4*)(Cv + (long long)r * ldc + bn0 + tx * TN + j4) = v;
    }
  }
}

// ---------------------------------------------------------------------------
// MFMA QP GEMM: [Q|P] = A1[M,256] @ Wab[256,128] + bab, bf16x2-split,
// 3 products (hi*hi + hi*lo + lo*hi) -> ~1e-5 relative (fp32-class).
// Block = 256 thr = 4 waves; wave w owns rows [bm0+16w, +16), all 128 cols.
// A staged fp32->LDS as hi/lo bf16 planes; W fragments pre-packed per-lane.
// C/D layout (m89-verified): col=lane&15, row=(lane>>4)*4+reg.
// A/B k-slots use the same assumed mapping -> any k-permutation cancels.
// ---------------------------------------------------------------------------
__global__ __launch_bounds__(256)
void gemm_qp_mfma(const float* __restrict__ A1,
                  const ushort* __restrict__ Wfh,
                  const ushort* __restrict__ Wfl,
                  const float* __restrict__ bab,
                  float* __restrict__ Qb, float* __restrict__ Pb, int M)
{
  __shared__ ushort LAh[64][32];
  __shared__ ushort LAl[64][32];
  const int tid = threadIdx.x;
  const int w = tid >> 6, l = tid & 63;
  const int bm0 = blockIdx.x * 64;
  const int srow = tid >> 2, skg = tid & 3;       // staging: row, k-group
  const int frow = (w << 4) + (l & 15);           // A-frag row (local)
  const int fk   = (l >> 4) << 3;                 // A-frag k offset

  f32x4 acc[8];
#pragma unroll
  for (int c = 0; c < 8; ++c) acc[c] = (f32x4){0.f, 0.f, 0.f, 0.f};

  for (int kt8 = 0; kt8 < 8; ++kt8) {
    // ---- stage A tile [64][32] -> hi/lo bf16 planes ----
    {
      int grow = bm0 + srow;
      float x[8];
      if (grow < M) {
        const float* ap = A1 + (size_t)grow * 256 + (kt8 << 5) + (skg << 3);
        *(float4*)&x[0] = *(const float4*)ap;
        *(float4*)&x[4] = *(const float4*)(ap + 4);
      } else {
#pragma unroll
        for (int j = 0; j < 8; ++j) x[j] = 0.f;
      }
      ushort h[8], lo[8];
#pragma unroll
      for (int j = 0; j < 8; ++j) {
        h[j] = f2bf(x[j]);
        lo[j] = f2bf(x[j] - bf2f(h[j]));
      }
      *(bf16x8*)&LAh[srow][skg << 3] = *(bf16x8*)h;
      *(bf16x8*)&LAl[srow][skg << 3] = *(bf16x8*)lo;
    }
    __syncthreads();

    bf16x8 ah = *(const bf16x8*)&LAh[frow][fk];
    bf16x8 al = *(const bf16x8*)&LAl[frow][fk];
#pragma unroll
    for (int ct = 0; ct < 8; ++ct) {
      size_t off = ((size_t)((kt8 << 3) + ct) * 64 + l) << 3;
      bf16x8 bh = *(const bf16x8*)(Wfh + off);
      bf16x8 bl = *(const bf16x8*)(Wfl + off);
      acc[ct] = __builtin_amdgcn_mfma_f32_16x16x32_bf16(ah, bh, acc[ct], 0, 0, 0);
      acc[ct] = __builtin_amdgcn_mfma_f32_16x16x32_bf16(ah, bl, acc[ct], 0, 0, 0);
      acc[ct] = __builtin_amdgcn_mfma_f32_16x16x32_bf16(al, bh, acc[ct], 0, 0, 0);
    }
    __syncthreads();
  }

  // ---- epilogue: split-store Q (cols 0-63) / P (cols 64-127) compact ----
  const int r0 = bm0 + (w << 4) + ((l >> 4) << 2);
#pragma unroll
  for (int ct = 0; ct < 8; ++ct) {
    int gcol = (ct << 4) + (l & 15);
    float bia = bab[gcol];
    float* dst = (gcol < 64) ? (Qb + gcol) : (Pb + (gcol - 64));
#pragma unroll
    for (int r = 0; r < 4; ++r) {
      int grow = r0 + r;
      if (grow < M) dst[(size_t)grow * 64] = acc[ct][r] + bia;
    }
  }
}

// Pack Wab[256,128] into per-lane MFMA fragment order, bf16 hi/lo planes.
// frag f = kt*8+ct; lane l supplies B[k=(l>>4)*8+j][col=ct*16+(l&15)].
__global__ __launch_bounds__(256)
void wfrag_k(const float* __restrict__ Wab, ushort* __restrict__ Wfh,
             ushort* __restrict__ Wfl)
{
  int t = blockIdx.x * 256 + threadIdx.x;   // 4096 total
  if (t >= 4096) return;
  int f = t >> 6, l = t & 63;
  int kt = f >> 3, ct = f & 7;
  int row0 = (kt << 5) + ((l >> 4) << 3);
  int col = (ct << 4) + (l & 15);
  ushort h[8], lo[8];
#pragma unroll
  for (int j = 0; j < 8; ++j) {
    float x = Wab[(row0 + j) * 128 + col];
    h[j] = f2bf(x);
    lo[j] = f2bf(x - bf2f(h[j]));
  }
  size_t off = ((size_t)t) << 3;
  *(bf16x8*)(Wfh + off) = *(bf16x8*)h;
  *(bf16x8*)(Wfl + off) = *(bf16x8*)lo;
}

// ---------------------------------------------------------------------------
// Weight fusion stage 1: T1 = wgc1@wgc2, T2 = lin1@wgc2, ta = bgc1@wgc2,
// tb = lin1b@wgc2  (all K=128 dots)
// ---------------------------------------------------------------------------
__global__ __launch_bounds__(256)
void fuse1_k(const float* __restrict__ wgc1, const float* __restrict__ lin1,
             const float* __restrict__ bgc1, const float* __restrict__ lin1b,
             const float* __restrict__ wgc2,
             float* __restrict__ T1, float* __restrict__ T2,
             float* __restrict__ ta, float* __restrict__ tb)
{
  int t = blockIdx.x * 256 + threadIdx.x;
  const float* Arow; float* outp; int n;
  if (t < 32768)      { n = t & 127; Arow = wgc1 + (t >> 7) * 128; outp = T1 + t; }
  else if (t < 65536) { int u = t - 32768; n = u & 127; Arow = lin1 + (u >> 7) * 128; outp = T2 + u; }
  else if (t < 65664) { n = t - 65536; Arow = bgc1;  outp = ta + n; }
  else if (t < 65792) { n = t - 65664; Arow = lin1b; outp = tb + n; }
  else return;
  float s = 0.f;
  for (int k = 0; k < 128; ++k) s = fmaf(Arow[k], wgc2[k * 128 + n], s);
  *outp = s;
}

// ---------------------------------------------------------------------------
// Weight fusion stage 2: Wab[:,0:64] = T1@w2, Wab[:,64:128] = T2@w2,
// bab = [ta@w2 | tb@w2], bc = bgc2@w2
// ---------------------------------------------------------------------------
__global__ __launch_bounds__(256)
void fuse2_k(const float* __restrict__ T1, const float* __restrict__ T2,
             const float* __restrict__ ta, const float* __restrict__ tb,
             const float* __restrict__ bgc2, const float* __restrict__ w2,
             float* __restrict__ Wab, float* __restrict__ bab,
             float* __restrict__ bcv)
{
  int t = blockIdx.x * 256 + threadIdx.x;
  const float* Arow; float* outp; int j;
  if (t < 32768) {
    int c = t & 127; j = c & 63;
    Arow = (c < 64 ? T1 : T2) + (t >> 7) * 128;
    outp = Wab + t;
  } else if (t < 32896) {
    int c = t - 32768; j = c & 63; Arow = (c < 64) ? ta : tb; outp = bab + c;
  } else if (t < 32960) {
    j = t - 32896; Arow = bgc2; outp = bcv + j;
  } else return;
  float s = 0.f;
  for (int k = 0; k < 128; ++k) s = fmaf(Arow[k], w2[k * 64 + j], s);
  *outp = s;
}

// ---------------------------------------------------------------------------
// CSR build v3: coarse count -> 1-block scan -> bin (bucket-grouped (d,s,w))
// -> sort (per-bucket LDS fine histogram + scan -> rp + packed sw).
// ---------------------------------------------------------------------------
__global__ __launch_bounds__(256)
void cnt_k(const int* __restrict__ edst, int* __restrict__ gbkt)
{
  __shared__ int l[NB];
  const int tid = threadIdx.x;
  for (int i = tid; i < NB; i += 256) l[i] = 0;
  __syncthreads();
  const int e0 = blockIdx.x * EPB;
  const int e1 = min(EE, e0 + EPB);
#pragma unroll
  for (int u = 0; u < 16; ++u) {
    int e = e0 + u * 256 + tid;
    if (e < e1) atomicAdd(&l[edst[e] >> BSH], 1);
  }
  __syncthreads();
  for (int i = tid; i < NB; i += 256)
    if (l[i]) atomicAdd(&gbkt[i], l[i]);
}

__global__ __launch_bounds__(256)
void scanB_k(const int* __restrict__ gbkt, int* __restrict__ bbase,
             int* __restrict__ gcur, int* __restrict__ rp)
{
  __shared__ int s[256];
  int t = threadIdx.x;
  int v = (t < NB) ? gbkt[t] : 0;
  s[t] = v;
  __syncthreads();
  for (int off = 1; off < 256; off <<= 1) {
    int u = (t >= off) ? s[t - off] : 0;
    __syncthreads();
    s[t] += u;
    __syncthreads();
  }
  if (t < NB) {
    int ex = s[t] - v;
    bbase[t] = ex;
    gcur[t] = ex;
  }
  if (t == 0) { bbase[NB] = EE; rp[NN] = EE; }
}

__global__ __launch_bounds__(256)
void bin_k(const int* __restrict__ edst, const int* __restrict__ esrc,
           const float* __restrict__ ew, int* __restrict__ gcur,
           int4* __restrict__ ebd)
{
  __shared__ int lcnt[NB];
  __shared__ int lbase[NB];
  const int tid = threadIdx.x;
  const int e0 = blockIdx.x * EPB;
  const int e1 = min(EE, e0 + EPB);
  for (int i = tid; i < NB; i += 256) lcnt[i] = 0;
  __syncthreads();
  int dv[16], sv[16], wv[16];
#pragma unroll
  for (int u = 0; u < 16; ++u) {
    int e = e0 + u * 256 + tid;
    if (e < e1) {
      dv[u] = edst[e];
      sv[u] = esrc[e];
      wv[u] = __float_as_int(ew[e]);
      atomicAdd(&lcnt[dv[u] >> BSH], 1);
    } else dv[u] = -1;
  }
  __syncthreads();
  for (int i = tid; i < NB; i += 256) {
    lbase[i] = atomicAdd(&gcur[i], lcnt[i]);
    lcnt[i] = 0;
  }
  __syncthreads();
#pragma unroll
  for (int u = 0; u < 16; ++u) {
    if (dv[u] >= 0) {
      int c = dv[u] >> BSH;
      int k = atomicAdd(&lcnt[c], 1);
      int4 p; p.x = dv[u]; p.y = sv[u]; p.z = wv[u]; p.w = 0;
      ebd[lbase[c] + k] = p;
    }
  }
}

__global__ __launch_bounds__(256)
void sort_k(const int4* __restrict__ ebd, const int* __restrict__ bbase,
            int* __restrict__ rp, int2* __restrict__ sw)
{
  __shared__ int hist[512];
  __shared__ int excl[512];
  __shared__ int s2[256];
  __shared__ int lcur[512];
  const int c = blockIdx.x;
  const int n0 = c << BSH;
  const int n1 = min(NN, n0 + 512);
  const int nn = n1 - n0;
  const int tid = threadIdx.x;
  for (int i = tid; i < 512; i += 256) { hist[i] = 0; lcur[i] = 0; }
  __syncthreads();
  const int b0 = bbase[c];
  const int b1 = bbase[c + 1];
  for (int i = b0 + tid; i < b1; i += 256)
    atomicAdd(&hist[ebd[i].x - n0], 1);
  __syncthreads();
  int a0 = hist[2 * tid], a1 = hist[2 * tid + 1];
  s2[tid] = a0 + a1;
  __syncthreads();
  for (int off = 1; off < 256; off <<= 1) {
    int u = (tid >= off) ? s2[tid - off] : 0;
    __syncthreads();
    s2[tid] += u;
    __syncthreads();
  }
  int pe = tid ? s2[tid - 1] : 0;
  excl[2 * tid] = pe;
  excl[2 * tid + 1] = pe + a0;
  if (2 * tid < nn)     rp[n0 + 2 * tid]     = b0 + pe;
  if (2 * tid + 1 < nn) rp[n0 + 2 * tid + 1] = b0 + pe + a0;
  __syncthreads();
  for (int i = b0 + tid; i < b1; i += 256) {
    int4 p = ebd[i];
    int li = p.x - n0;
    int k = atomicAdd(&lcur[li], 1);
    int2 q; q.x = p.y; q.y = p.z;
    sw[b0 + excl[li] + k] = q;
  }
}

// ---------------------------------------------------------------------------
// CSR spmm on compact 64-wide f32 rows: one wave per dst node, lane owns one
// column. Int fixed-point accumulate -> bit-deterministic.
//  MODE 1: out = acc*INVS + bias[lane]
//  MODE 2: out = n[d]*P[d,lane] + (1-n[d])*acc*INVS + bias[lane]
// ---------------------------------------------------------------------------
template<int MODE>
__global__ __launch_bounds__(256)
void spmm64(const int* __restrict__ rp, const int2* __restrict__ sw,
            const float* __restrict__ Gf, float* __restrict__ xout,
            const float* __restrict__ bias, const float* __restrict__ npar,
            const float* __restrict__ Pb)
{
  int widx = blockIdx.x * 4 + (threadIdx.x >> 6);
  if (widx >= NN) return;
  int lane = threadIdx.x & 63;
  int e0 = rp[widx], e1 = rp[widx + 1];
  int acc = 0;
  int j = e0;
  for (; j + 8 <= e1; j += 8) {
    float gv[8], wv[8];
#pragma unroll
    for (int u = 0; u < 8; ++u) {
      int2 q = sw[j + u];                       // wave-uniform -> broadcast
      wv[u] = __int_as_float(q.y);
      gv[u] = Gf[(size_t)q.x * 64 + lane];
    }
#pragma unroll
    for (int u = 0; u < 8; ++u)
      acc += __float2int_rn(gv[u] * wv[u] * FIXS);
  }
  for (; j < e1; ++j) {
    int2 q = sw[j];
    acc += __float2int_rn(Gf[(size_t)q.x * 64 + lane] *
                          __int_as_float(q.y) * FIXS);
  }
  float v = (float)acc * INVS;
  if (MODE == 1) {
    xout[(size_t)widx * 64 + lane] = v + bias[lane];
  } else {
    float nv = npar[widx];
    float p = Pb[(size_t)widx * 64 + lane];
    xout[(size_t)widx * 64 + lane] = nv * p + (1.f - nv) * v + bias[lane];
  }
}

// ---------------------------------------------------------------------------
// S[b,:] = sum_l Z[bidx[b,l],:] - 49*b2
// ---------------------------------------------------------------------------
__global__ __launch_bounds__(256)
void sumS_k(const float* __restrict__ Z, const int* __restrict__ bidx,
            const float* __restrict__ b2, float* __restrict__ S)
{
  int wv = threadIdx.x >> 6;
  int lane = threadIdx.x & 63;
  int b = blockIdx.x * 4 + wv;
  if (b >= BBB) return;
  const int* bi = bidx + (size_t)b * LLL;
  float s = 0.f;
  for (int l = 0; l < LLL; ++l)
    s += Z[(size_t)bi[l] * 64 + lane];
  S[(size_t)b * 64 + lane] = s - 49.f * b2[lane];
}

// ---------------------------------------------------------------------------
// sel = P4[0]+P4[1]+P4[2]+P4[3] + l1b  (fixed order -> deterministic)
// ---------------------------------------------------------------------------
__global__ __launch_bounds__(256)
void reduce4_k(const float* __restrict__ P4, const float* __restrict__ l1b,
               float* __restrict__ sel)
{
  int t = blockIdx.x * 256 + threadIdx.x;
  if (t >= BBB * 32) return;
  int r = t >> 5, c4 = t & 31;
  size_t off = (size_t)r * 128 + (c4 << 2);
  const size_t zs = (size_t)BBB * 128;
  float4 s0 = *(const float4*)(P4 + off);
  float4 s1 = *(const float4*)(P4 + zs + off);
  float4 s2 = *(const float4*)(P4 + 2 * zs + off);
  float4 s3 = *(const float4*)(P4 + 3 * zs + off);
  float4 b  = *(const float4*)(l1b + (c4 << 2));
  float4 o;
  o.x = ((s0.x + s1.x) + s2.x) + s3.x + b.x;
  o.y = ((s0.y + s1.y) + s2.y) + s3.y + b.y;
  o.z = ((s0.z + s1.z) + s2.z) + s3.z + b.z;
  o.w = ((s0.w + s1.w) + s2.w) + s3.w + b.w;
  *(float4*)(sel + off) = o;
}

// ---------------------------------------------------------------------------
// Classifier + argmax (first-max tie-break, matches jnp.argmax).
// ---------------------------------------------------------------------------
__global__ __launch_bounds__(256)
void cls_k(const float* __restrict__ sel, const float* __restrict__ Wc,
           const float* __restrict__ bc, float* __restrict__ outIdx)
{
  int wv = threadIdx.x >> 6;
  int lane = threadIdx.x & 63;
  int b = blockIdx.x * 4 + wv;
  if (b >= BBB) return;
  float logit = -1e30f;
  if (lane < NCLS) {
    float s = bc[lane];
    const float* sr = sel + (size_t)b * DD;
    for (int d = 0; d < DD; ++d) s = fmaf(sr[d], Wc[d * NCLS + lane], s);
    logit = s;
  }
  float best = -1e30f; int bi = 0;
  for (int c = 0; c < NCLS; ++c) {
    float v = __shfl(logit, c, 64);
    if (v > best) { best = v; bi = c; }
  }
  if (lane == 0) outIdx[b] = (float)bi;
}

// ---------------------------------------------------------------------------
extern "C" void kernel_launch(void* const* d_in, const int* in_sizes, int n_in,
                              void* d_out, int out_size, void* d_ws, size_t ws_size,
                              hipStream_t stream)
{
  const float* A1    = (const float*)d_in[0];
  const int*   esrc  = (const int*)d_in[1];
  const int*   edst  = (const int*)d_in[2];
  const float* ew    = (const float*)d_in[3];
  const int*   bidx  = (const int*)d_in[4];   // [B,1,L] == [B*L]
  const float* wgc1  = (const float*)d_in[5];
  const float* bgc1  = (const float*)d_in[6];
  const float* wgc2  = (const float*)d_in[7];
  const float* bgc2  = (const float*)d_in[8];
  const float* npar  = (const float*)d_in[9];
  const float* lin1  = (const float*)d_in[10];
  const float* lin1b = (const float*)d_in[11];
  const float* w2    = (const float*)d_in[12];
  const float* b2    = (const float*)d_in[13];
  const float* l1w   = (const float*)d_in[14];
  const float* l1b   = (const float*)d_in[15];
  const float* clsw  = (const float*)d_in[16];
  const float* clsb  = (const float*)d_in[17];

  float* out = (float*)d_out;
  float* sel = out + BBB;

  // workspace layout (peak ~92.0 MB; proven floor from round 1 is 104.67 MB)
  uint8_t* ws   = (uint8_t*)d_ws;
  int4*    ebd  = (int4*) (ws);                 // 25.6 MB (CSR build)
  float*   Qb   = (float*)(ws);                 // 25.6 MB (after sort_k)
  float*   Z    = (float*)(ws);                 // 25.6 MB (after spmm1)
  float*   Pb   = (float*)(ws + 25600000);      // 25.6 MB
  float*   G    = (float*)(ws + 51200000);      // 25.6 MB
  float*   P4   = (float*)(ws + 51200000);      //  8.4 MB (after spmm2)
  int2*    sw   = (int2*) (ws + 76800000);      // 12.8 MB packed (src,w)
  int*     rp   = (int*)  (ws + 89600000);      //  0.4 MB (N+1)
  int*     gbkt = (int*)  (ws + 90000016);      //  784 B
  int*     gcur = (int*)  (ws + 90001040);      //  784 B
  int*     bbase= (int*)  (ws + 90002064);      //  788 B
  float*   S    = (float*)(ws + 90400528);      //  1.0 MB [B,64]
  float*   T1   = (float*)(ws + 91449104);      // 128 KB
  float*   T2   = (float*)(ws + 91580176);      // 128 KB
  float*   Wab  = (float*)(ws + 91711248);      // 128 KB [256,128]
  float*   ta   = (float*)(ws + 91842320);      // 512 B
  float*   tb   = (float*)(ws + 91842832);      // 512 B
  float*   bab  = (float*)(ws + 91843344);      // 512 B [128]
  float*   bcv  = (float*)(ws + 91843856);      // 256 B [64]
  ushort*  Wfh  = (ushort*)(ws + 91844112);     //  64 KB W frag hi
  ushort*  Wfl  = (ushort*)(ws + 91909648);     //  64 KB W frag lo

  dim3 blk(256);
  const int gEB = (EE + EPB - 1) / EPB;         // 391

  // ---- weight fusion + MFMA fragment pack ----
  hipLaunchKernelGGL(fuse1_k, dim3(257), blk, 0, stream,
      wgc1, lin1, bgc1, lin1b, wgc2, T1, T2, ta, tb);
  hipLaunchKernelGGL(fuse2_k, dim3(129), blk, 0, stream,
      T1, T2, ta, tb, bgc2, w2, Wab, bab, bcv);
  hipLaunchKernelGGL(wfrag_k, dim3(16), blk, 0, stream, Wab, Wfh, Wfl);

  // ---- CSR build (coarse count -> scan -> bin -> per-bucket sort) ----
  hipMemsetAsync(gbkt, 0, NB * 4, stream);
  hipLaunchKernelGGL(cnt_k, dim3(gEB), blk, 0, stream, edst, gbkt);
  hipLaunchKernelGGL(scanB_k, dim3(1), blk, 0, stream, gbkt, bbase, gcur, rp);
  hipLaunchKernelGGL(bin_k, dim3(gEB), blk, 0, stream, edst, esrc, ew, gcur, ebd);
  hipLaunchKernelGGL(sort_k, dim3(NB), blk, 0, stream, ebd, bbase, rp, sw);

  // ---- Q|P = A1 @ Wab + bab via bf16x2-split MFMA (compact [N,64] each) ----
  hipLaunchKernelGGL(gemm_qp_mfma, dim3(1563), blk, 0, stream,
      A1, Wfh, Wfl, bab, Qb, Pb, NN);

  // ---- G = n*P + (1-n)*spmm(Q) + bc ----
  hipLaunchKernelGGL((spmm64<2>), dim3(NN / 4), blk, 0, stream,
      rp, sw, Qb, G, bcv, npar, Pb);

  // ---- Z = spmm(G) + b2  [N,64] (overwrites Qbuf) ----
  hipLaunchKernelGGL((spmm64<1>), dim3(NN / 4), blk, 0, stream,
      rp, sw, G, Z, b2, (const float*)nullptr, (const float*)nullptr);

  // ---- S[b] = sum_l Z[bidx[b,l]] - 49*b2 ----
  hipLaunchKernelGGL(sumS_k, dim3(BBB / 4), blk, 0, stream, Z, bidx, b2, S);

  // ---- P4[z] = [gather(Z)|S] @ l1w (K-chunk z)  grid (128,2,4) ----
  hipLaunchKernelGGL((gemm_f32<32,64,32,2,4>), dim3(BBB / 32, 2, 4), blk, 0, stream,
      Z, 64, l1w, DD, (const float*)nullptr, P4, DD,
      BBB, (LLL + 1) * 64, 13 * 64, bidx, S);

  // ---- sel = sum_z P4[z] + l1b ----
  hipLaunchKernelGGL(reduce4_k, dim3(BBB * 32 / 256), blk, 0, stream, P4, l1b, sel);

  // ---- argmax(sel @ classifier + bias) -> out[0:B] ----
  hipLaunchKernelGGL(cls_k, dim3(BBB / 4), blk, 0, stream, sel, clsw, clsb, out);
}